// Round 6
// baseline (242.482 us; speedup 1.0000x reference)
//
#include <hip/hip_runtime.h>
#include <stdint.h>

#define KQ     8     // queries per knn block
#define KNB    16
#define CAPC   256   // LDS survivor cap per (query, chunk); E~54, tail-safe
#define CAPG   512   // global candidate cap per query; E~216
#define NCHUNK 4

typedef short short8 __attribute__((ext_vector_type(8)));
typedef float floatx4 __attribute__((ext_vector_type(4)));
typedef float floatx2 __attribute__((ext_vector_type(2)));

__device__ __forceinline__ unsigned short f2bf(float x) {
  union { float f; uint32_t u; } v; v.f = x;
  uint32_t u = v.u + 0x7FFFu + ((v.u >> 16) & 1u);   // RNE
  return (unsigned short)(u >> 16);
}
__device__ __forceinline__ float bf2f(unsigned short b) {
  return __uint_as_float(((uint32_t)b) << 16);
}
__device__ __forceinline__ float rfl(float v) {   // wave-uniform -> SGPR
  return __int_as_float(__builtin_amdgcn_readfirstlane(__float_as_int(v)));
}

static __device__ __forceinline__ floatx2 fma2(floatx2 a, floatx2 b, floatx2 c) {
#if __has_builtin(__builtin_elementwise_fma)
  return __builtin_elementwise_fma(a, b, c);
#else
  floatx2 r; r[0] = fmaf(a[0], b[0], c[0]); r[1] = fmaf(a[1], b[1], c[1]);
  return r;
#endif
}
static __device__ __forceinline__ floatx2 min2(floatx2 a, floatx2 b) {
#if __has_builtin(__builtin_elementwise_min)
  return __builtin_elementwise_min(a, b);
#else
  floatx2 r; r[0] = fminf(a[0], b[0]); r[1] = fminf(a[1], b[1]);
  return r;
#endif
}
static __device__ __forceinline__ floatx2 sp2(float v) {
  floatx2 r; r[0] = v; r[1] = v; return r;
}

// ---------------------------------------------------------------------------
// prep: pos4={x,y,z,pp}; pospk pair-SoA {x0,x1,y0,y1,z0,z1,pp0,pp1} with
// pp=3e38 sentinels to Npad2; Wt = bf16 W_att^T; cnt_g zeroed.
// ---------------------------------------------------------------------------
__global__ void prep_kernel(const float* __restrict__ pos,
                            const float* __restrict__ W_att,
                            float4* __restrict__ pos4,
                            float* __restrict__ pospk,
                            unsigned short* __restrict__ Wt,
                            int* __restrict__ cnt_g, int N, int Npad2, int M) {
  int id = blockIdx.x * 256 + threadIdx.x;
  if (id < Npad2) {
    int j = id;
    float px = 0.f, py = 0.f, pz = 0.f, pp = 3.0e38f;
    if (j < N) {
      px = pos[3 * j]; py = pos[3 * j + 1]; pz = pos[3 * j + 2];
      pp = fmaf(px, px, fmaf(py, py, pz * pz));
      pos4[j] = make_float4(px, py, pz, pp);
    }
    int pair = j >> 1, h = j & 1;
    float* dst = pospk + (size_t)pair * 8;
    dst[0 + h] = px; dst[2 + h] = py; dst[4 + h] = pz; dst[6 + h] = pp;
  } else if (id < Npad2 + 128 * 128) {
    int t = id - Npad2;
    int c = t >> 7, f = t & 127;
    Wt[f * 128 + c] = f2bf(W_att[t]);
  } else if (id < Npad2 + 128 * 128 + M) {
    cnt_g[id - Npad2 - 128 * 128] = 0;
  }
}

// ---------------------------------------------------------------------------
// knn: threshold-select over NCHUNK=4 point-chunks per query-group (grid =
// 938*4 blocks for occupancy). Pass 1: FULL chunk scan, tau = max of 16
// disjoint group mins (+margin) >= chunk's 16th-smallest t, so the chunk
// contributes >=16 witnesses and any global top-16 point in this chunk has
// t <= global t16 <= chunk t16 <= tau -> collected. Pass 2 (bitwise-identical
// t expression) collects indices; pass 3 appends to global per-query list.
// ---------------------------------------------------------------------------
__global__ __launch_bounds__(256) void knn_kernel(
    const float4* __restrict__ pos4, const float4* __restrict__ pospk4,
    const int* __restrict__ idx, uint32_t* __restrict__ cand_g,
    int* __restrict__ cnt_g, int Npad2, int M) {
  __shared__ uint32_t cand[KQ][CAPC];
  __shared__ int cnt[KQ];
  __shared__ float gmin[KQ][16];
  __shared__ float tau_s[KQ];

  const int tid = threadIdx.x;
  const int wid = tid >> 6, lane = tid & 63;
  const int qg = blockIdx.x >> 2, chunk = blockIdx.x & 3;
  const int q0 = qg * KQ;
  const int iters = Npad2 >> 11;            // points/chunk / 512 (= 15)
  const int pbase = chunk * (Npad2 >> 3);   // pair-index base of chunk
  const int jbase = chunk * (Npad2 >> 2);   // point-id base of chunk

  float sx[KQ], sy[KQ], sz[KQ];
#pragma unroll
  for (int qi = 0; qi < KQ; ++qi) {
    int m = q0 + qi; if (m >= M) m = M - 1;
    float4 qp = pos4[idx[m]];
    sx[qi] = rfl(-2.f * qp.x); sy[qi] = rfl(-2.f * qp.y);
    sz[qi] = rfl(-2.f * qp.z);
  }
  if (tid < KQ) cnt[tid] = 0;

  // ---- pass 1: full-chunk per-lane t-mins, prefetched stream ----
  floatx2 tmn[KQ];
#pragma unroll
  for (int qi = 0; qi < KQ; ++qi) tmn[qi] = sp2(3.4e38f);
  {
    int pg = (pbase + tid) * 2;
    float4 a = pospk4[pg], b = pospk4[pg + 1];
    for (int it = 0; it < iters; ++it) {
      float4 an = a, bn = b;
      if (it + 1 < iters) {
        int pgn = (pbase + (it + 1) * 256 + tid) * 2;
        an = pospk4[pgn]; bn = pospk4[pgn + 1];
      }
      floatx2 X, Y, Z, W;
      X[0] = a.x; X[1] = a.y; Y[0] = a.z; Y[1] = a.w;
      Z[0] = b.x; Z[1] = b.y; W[0] = b.z; W[1] = b.w;
#pragma unroll
      for (int qi = 0; qi < KQ; ++qi) {
        floatx2 t = fma2(sp2(sx[qi]), X,
                         fma2(sp2(sy[qi]), Y, fma2(sp2(sz[qi]), Z, W)));
        tmn[qi] = min2(tmn[qi], t);
      }
      a = an; b = bn;
    }
  }
  // 16 disjoint thread-groups -> group mins -> tau
#pragma unroll
  for (int qi = 0; qi < KQ; ++qi) {
    float v = fminf(tmn[qi][0], tmn[qi][1]);
    v = fminf(v, __shfl_xor(v, 1));
    v = fminf(v, __shfl_xor(v, 2));
    v = fminf(v, __shfl_xor(v, 4));
    v = fminf(v, __shfl_xor(v, 8));
    if ((tid & 15) == 0) gmin[qi][tid >> 4] = v;
  }
  __syncthreads();
  if (tid < KQ) {
    float t = gmin[tid][0];
#pragma unroll
    for (int g = 1; g < 16; ++g) t = fmaxf(t, gmin[tid][g]);
    tau_s[tid] = t + fabsf(t) * 1e-6f + 1e-7f;
  }
  __syncthreads();
  float tau[KQ];
#pragma unroll
  for (int qi = 0; qi < KQ; ++qi) tau[qi] = rfl(tau_s[qi]);

  // ---- pass 2: re-stream chunk, collect survivor indices ----
  {
    int pg = (pbase + tid) * 2;
    float4 a = pospk4[pg], b = pospk4[pg + 1];
    for (int it = 0; it < iters; ++it) {
      float4 an = a, bn = b;
      if (it + 1 < iters) {
        int pgn = (pbase + (it + 1) * 256 + tid) * 2;
        an = pospk4[pgn]; bn = pospk4[pgn + 1];
      }
      floatx2 X, Y, Z, W;
      X[0] = a.x; X[1] = a.y; Y[0] = a.z; Y[1] = a.w;
      Z[0] = b.x; Z[1] = b.y; W[0] = b.z; W[1] = b.w;
      const int j0 = jbase + it * 512 + tid * 2;
#pragma unroll
      for (int qi = 0; qi < KQ; ++qi) {
        floatx2 t = fma2(sp2(sx[qi]), X,
                         fma2(sp2(sy[qi]), Y, fma2(sp2(sz[qi]), Z, W)));
        if (fminf(t[0], t[1]) <= tau[qi]) {
          if (t[0] <= tau[qi]) {
            int sl = atomicAdd(&cnt[qi], 1);
            if (sl < CAPC) cand[qi][sl] = (uint32_t)j0;
          }
          if (t[1] <= tau[qi]) {
            int sl = atomicAdd(&cnt[qi], 1);
            if (sl < CAPC) cand[qi][sl] = (uint32_t)(j0 + 1);
          }
        }
      }
      a = an; b = bn;
    }
  }
  __syncthreads();

  // ---- pass 3: append survivors to global per-query list ----
#pragma unroll
  for (int i = 0; i < 2; ++i) {
    int qi = wid * 2 + i;
    int m = q0 + qi;
    if (m < M) {
      int nc = cnt[qi]; if (nc > CAPC) nc = CAPC;
      int base = 0;
      if (lane == 0) base = atomicAdd(&cnt_g[m], nc);
      base = __shfl(base, 0);
      for (int s = lane; s < nc; s += 64) {
        int p = base + s;
        if (p < CAPG) cand_g[(size_t)m * CAPG + p] = cand[qi][s];
      }
    }
  }
}

// ---------------------------------------------------------------------------
// merge: per query (1 wave), exact f32 d2 over <=CAPG candidates, extract
// the 16 smallest (d2,idx)-packed u64s. Deterministic despite append order.
// ---------------------------------------------------------------------------
__global__ __launch_bounds__(256) void merge_kernel(
    const float4* __restrict__ pos4, const int* __restrict__ idx,
    const uint32_t* __restrict__ cand_g, const int* __restrict__ cnt_g,
    int* __restrict__ nbr, int M) {
  const int tid = threadIdx.x;
  const int lane = tid & 63;
  const int m = blockIdx.x * 4 + (tid >> 6);
  if (m >= M) return;

  float4 qp = pos4[idx[m]];
  int nc = cnt_g[m]; if (nc > CAPG) nc = CAPG;

  unsigned long long c[CAPG / 64];
#pragma unroll
  for (int ch = 0; ch < CAPG / 64; ++ch) {
    c[ch] = ~0ull;
    int s = ch * 64 + lane;
    if (s < nc) {
      uint32_t j = cand_g[(size_t)m * CAPG + s];
      float4 pj = pos4[j];
      float dot = fmaf(qp.x, pj.x, fmaf(qp.y, pj.y, qp.z * pj.z));
      float tt  = fmaf(-2.f, dot, pj.w);
      float d2  = fmaxf(qp.w + tt, 0.f);
      c[ch] = ((unsigned long long)__float_as_uint(d2) << 32) | j;
    }
  }
#pragma unroll
  for (int r = 0; r < KNB; ++r) {
    unsigned long long mn = c[0];
#pragma unroll
    for (int ch = 1; ch < CAPG / 64; ++ch) mn = (c[ch] < mn) ? c[ch] : mn;
#pragma unroll
    for (int off = 1; off < 64; off <<= 1) {
      unsigned long long o = __shfl_xor(mn, off);
      mn = (o < mn) ? o : mn;
    }
    if (lane == 0) nbr[m * KNB + r] = (int)(uint32_t)mn;
#pragma unroll
    for (int ch = 0; ch < CAPG / 64; ++ch)
      if (c[ch] == mn) c[ch] = ~0ull;
  }
}

// ---------------------------------------------------------------------------
// mid: 8 queries / 256-thread block; f32 x gather -> bf16 LDS; bf16-MFMA
// attention matvec; softmax over features; mean over K.
// ---------------------------------------------------------------------------
__global__ __launch_bounds__(256) void mid_kernel(
    const float* __restrict__ x, const float4* __restrict__ pos4,
    const int* __restrict__ idx, const float* __restrict__ W_pos,
    const float* __restrict__ b_pos, const unsigned short* __restrict__ Wt,
    const float* __restrict__ b_att, const int* __restrict__ nbr,
    float* __restrict__ aggr, int M) {
  __shared__ __align__(16) unsigned short fijb[8][16][136];
  __shared__ int nbr_s[128];
  __shared__ float4 qpos_s[8];

  const int tid = threadIdx.x;
  const int wid = tid >> 6, lane = tid & 63;
  const int col = lane & 15, quad = lane >> 4;
  const int b = blockIdx.x;

  if (tid < 128) {
    int mq = b * 8 + (tid >> 4); if (mq >= M) mq = M - 1;
    nbr_s[tid] = nbr[mq * 16 + (tid & 15)];
  }
  if (tid < 8) {
    int mq = b * 8 + tid; if (mq >= M) mq = M - 1;
    qpos_s[tid] = pos4[idx[mq]];
  }
  float wp[10];
#pragma unroll
  for (int t = 0; t < 10; ++t) wp[t] = W_pos[t * 64 + lane];
  float bp = b_pos[lane];
  __syncthreads();

  // x gather: 2 threads per (q,k) row, f32 -> bf16
  {
    int rr = tid >> 1, h = tid & 1;
    int jn = nbr_s[rr];
    const float4* src = (const float4*)(x + (size_t)jn * 64) + h * 8;
    short8* dst = (short8*)&fijb[rr >> 4][rr & 15][h * 32];
#pragma unroll
    for (int i = 0; i < 4; ++i) {
      float4 u = src[2 * i], v = src[2 * i + 1];
      short8 w;
      w[0] = (short)f2bf(u.x); w[1] = (short)f2bf(u.y);
      w[2] = (short)f2bf(u.z); w[3] = (short)f2bf(u.w);
      w[4] = (short)f2bf(v.x); w[5] = (short)f2bf(v.y);
      w[6] = (short)f2bf(v.z); w[7] = (short)f2bf(v.w);
      dst[i] = w;
    }
  }
  // LocSE rij (bf16), wave handles 2 queries, lane = channel
#pragma unroll
  for (int qi = 0; qi < 2; ++qi) {
    int q = wid * 2 + qi;
    float4 qp = qpos_s[q];
#pragma unroll 4
    for (int k = 0; k < 16; ++k) {
      int jn = nbr_s[q * 16 + k];
      float4 pj = pos4[jn];
      float vx = qp.x - pj.x, vy = qp.y - pj.y, vz = qp.z - pj.z;
      float dd = sqrtf(fmaf(vx, vx, fmaf(vy, vy, vz * vz)));
      float r = bp;
      r = fmaf(qp.x, wp[0], r); r = fmaf(qp.y, wp[1], r); r = fmaf(qp.z, wp[2], r);
      r = fmaf(pj.x, wp[3], r); r = fmaf(pj.y, wp[4], r); r = fmaf(pj.z, wp[5], r);
      r = fmaf(vx, wp[6], r);  r = fmaf(vy, wp[7], r);  r = fmaf(vz, wp[8], r);
      r = fmaf(dd, wp[9], r);
      r = fmaxf(r, 0.f);
      fijb[q][k][64 + lane] = f2bf(r);
    }
  }
  __syncthreads();

#pragma unroll 1
  for (int qi = 0; qi < 2; ++qi) {
    int q = wid * 2 + qi;
    int mq = b * 8 + q;

    short8 af[4];
#pragma unroll
    for (int cs = 0; cs < 4; ++cs)
      af[cs] = *(const short8*)&fijb[q][col][cs * 32 + quad * 8];

    floatx4 acc[8];
#pragma unroll
    for (int ft = 0; ft < 8; ++ft) {
      float bav = b_att[ft * 16 + col];
      floatx4 a = {bav, bav, bav, bav};
#pragma unroll
      for (int cs = 0; cs < 4; ++cs) {
        short8 bfrag =
            *(const short8*)&Wt[(ft * 16 + col) * 128 + cs * 32 + quad * 8];
        a = __builtin_amdgcn_mfma_f32_16x16x32_bf16(af[cs], bfrag, a, 0, 0, 0);
      }
      acc[ft] = a;
    }

    float rowmax[4], rowinv[4];
#pragma unroll
    for (int r = 0; r < 4; ++r) {
      float mx = acc[0][r];
#pragma unroll
      for (int ft = 1; ft < 8; ++ft) mx = fmaxf(mx, acc[ft][r]);
      mx = fmaxf(mx, __shfl_xor(mx, 1));
      mx = fmaxf(mx, __shfl_xor(mx, 2));
      mx = fmaxf(mx, __shfl_xor(mx, 4));
      mx = fmaxf(mx, __shfl_xor(mx, 8));
      float sm = 0.f;
#pragma unroll
      for (int ft = 0; ft < 8; ++ft) sm += __expf(acc[ft][r] - mx);
      sm += __shfl_xor(sm, 1);
      sm += __shfl_xor(sm, 2);
      sm += __shfl_xor(sm, 4);
      sm += __shfl_xor(sm, 8);
      rowmax[r] = mx;
      rowinv[r] = 1.0f / sm;
    }

#pragma unroll
    for (int ft = 0; ft < 8; ++ft) {
      float ap = 0.f;
#pragma unroll
      for (int r = 0; r < 4; ++r) {
        float s = __expf(acc[ft][r] - rowmax[r]) * rowinv[r];
        float fv = bf2f(fijb[q][quad * 4 + r][ft * 16 + col]);
        ap = fmaf(s, fv, ap);
      }
      ap += __shfl_xor(ap, 16);
      ap += __shfl_xor(ap, 32);
      if (quad == 0 && mq < M)
        aggr[mq * 128 + ft * 16 + col] = ap * (1.0f / 16.0f);
    }
  }
}

// ---------------------------------------------------------------------------
// out = relu(aggr @ W_glob + b_glob)
// ---------------------------------------------------------------------------
__global__ __launch_bounds__(256) void out_kernel(
    const float* __restrict__ aggr, const float* __restrict__ W_glob,
    const float* __restrict__ b_glob, float* __restrict__ out, int M) {
  __shared__ float ag[16][128];
  const int tid = threadIdx.x;
  const int mbase = blockIdx.x * 16;
  for (int s = tid; s < 16 * 128; s += 256) {
    int r = s >> 7, cc = s & 127;
    int m = mbase + r;
    ((float*)ag)[s] = (m < M) ? aggr[m * 128 + cc] : 0.0f;
  }
  __syncthreads();
  const int f = tid & 127, h = tid >> 7;
  float acc[8];
  float bg = b_glob[f];
#pragma unroll
  for (int i = 0; i < 8; ++i) acc[i] = bg;
  for (int c = 0; c < 128; c += 4) {
    float w0 = W_glob[(c + 0) * 128 + f];
    float w1 = W_glob[(c + 1) * 128 + f];
    float w2 = W_glob[(c + 2) * 128 + f];
    float w3 = W_glob[(c + 3) * 128 + f];
#pragma unroll
    for (int i = 0; i < 8; ++i) {
      const floatx4 a4 = *(const floatx4*)&ag[h * 8 + i][c];
      acc[i] += a4[0] * w0 + a4[1] * w1 + a4[2] * w2 + a4[3] * w3;
    }
  }
#pragma unroll
  for (int i = 0; i < 8; ++i) {
    int m = mbase + h * 8 + i;
    if (m < M) out[m * 128 + f] = fmaxf(acc[i], 0.0f);
  }
}

// ---------------------------------------------------------------------------
extern "C" void kernel_launch(void* const* d_in, const int* in_sizes, int n_in,
                              void* d_out, int out_size, void* d_ws,
                              size_t ws_size, hipStream_t stream) {
  const float* x      = (const float*)d_in[0];
  const float* pos    = (const float*)d_in[1];
  const int*   idx    = (const int*)d_in[2];
  const float* W_pos  = (const float*)d_in[3];
  const float* b_pos  = (const float*)d_in[4];
  const float* W_att  = (const float*)d_in[5];
  const float* b_att  = (const float*)d_in[6];
  const float* W_glob = (const float*)d_in[7];
  const float* b_glob = (const float*)d_in[8];
  float* out = (float*)d_out;

  const int N = in_sizes[1] / 3;
  const int M = in_sizes[2];
  const int Npad2 = (N + 2047) & ~2047;   // 4 chunks x (Npad2/2048) iters

  char* ws = (char*)d_ws;
  size_t o = 0;
  float4* pos4 = (float4*)(ws + o);               o += ((size_t)N * 16 + 255) & ~(size_t)255;
  float* pospk = (float*)(ws + o);                o += ((size_t)Npad2 * 16 + 255) & ~(size_t)255;
  unsigned short* Wt = (unsigned short*)(ws + o); o += (128 * 128 * 2 + 255) & ~(size_t)255;
  int* nbr = (int*)(ws + o);                      o += (((size_t)M * KNB * 4) + 255) & ~(size_t)255;
  uint32_t* cand_g = (uint32_t*)(ws + o);         o += (((size_t)M * CAPG * 4) + 255) & ~(size_t)255;
  int* cnt_g = (int*)(ws + o);                    o += (((size_t)M * 4) + 255) & ~(size_t)255;
  float* aggr = (float*)(ws + o);

  int prep_ids = Npad2 + 128 * 128 + M;
  prep_kernel<<<(prep_ids + 255) / 256, 256, 0, stream>>>(
      pos, W_att, pos4, pospk, Wt, cnt_g, N, Npad2, M);
  knn_kernel<<<((M + KQ - 1) / KQ) * NCHUNK, 256, 0, stream>>>(
      pos4, (const float4*)pospk, idx, cand_g, cnt_g, Npad2, M);
  merge_kernel<<<(M + 3) / 4, 256, 0, stream>>>(pos4, idx, cand_g, cnt_g, nbr,
                                                M);
  mid_kernel<<<(M + 7) / 8, 256, 0, stream>>>(x, pos4, idx, W_pos, b_pos, Wt,
                                              b_att, nbr, aggr, M);
  out_kernel<<<(M + 15) / 16, 256, 0, stream>>>(aggr, W_glob, b_glob, out, M);
}